// Round 5
// baseline (269.377 us; speedup 1.0000x reference)
//
#include <hip/hip_runtime.h>
#include <math.h>

// Problem constants
constexpr int Bc  = 4;
constexpr int Sc  = 2048;
constexpr int Dc  = 512;
constexpr int Hc  = 8;
constexpr int DKc = 64;
constexpr int Mc  = Bc * Sc;   // 8192 rows

constexpr float SCALE_Q = 0.180336880111120426f;   // (1/8) * log2(e): /H quirk + exp2 base

typedef __attribute__((ext_vector_type(8)))  short s16x8;   // 8 bf16 MFMA frag
typedef __attribute__((ext_vector_type(4)))  float f32x4;   // 16x16 accumulator
typedef __attribute__((ext_vector_type(16))) float f32x16;  // 32x32 accumulator

__device__ __forceinline__ unsigned short f2bf(float f) {
    __bf16 h = (__bf16)f;                 // RNE convert
    return __builtin_bit_cast(unsigned short, h);
}

__device__ __forceinline__ float fexp2(float x) {
#if __has_builtin(__builtin_amdgcn_exp2f)
    return __builtin_amdgcn_exp2f(x);
#else
    return __expf(x * 0.6931471805599453f);
#endif
}

// ---------------------------------------------------------------------------
// mask [B,1,S,S] int32 -> keep-bit words: bit j of word w == (mask[w*64+j]!=0)
// ---------------------------------------------------------------------------
__global__ __launch_bounds__(256)
void pack_mask(const int* __restrict__ mask, unsigned long long* __restrict__ out,
               int nwords)
{
    int gw   = (blockIdx.x * blockDim.x + threadIdx.x) >> 6;
    int lane = threadIdx.x & 63;
    int nw   = (gridDim.x * blockDim.x) >> 6;
    for (int w0 = gw * 4; w0 < nwords; w0 += nw * 4) {
        int vals[4];
#pragma unroll
        for (int c = 0; c < 4; ++c)
            vals[c] = mask[(size_t)(w0 + c) * 64 + lane];
#pragma unroll
        for (int c = 0; c < 4; ++c) {
            unsigned long long bits = __ballot(vals[c] != 0);
            if (lane == 0) out[w0 + c] = bits;
        }
    }
}

// ---------------------------------------------------------------------------
// fp32 -> bf16 elementwise, up to 4 tensors (blockIdx.y selects), n4 float4s
// ---------------------------------------------------------------------------
__global__ __launch_bounds__(256)
void cvt4(const float* __restrict__ i0, const float* __restrict__ i1,
          const float* __restrict__ i2, const float* __restrict__ i3,
          unsigned short* __restrict__ o0, unsigned short* __restrict__ o1,
          unsigned short* __restrict__ o2, unsigned short* __restrict__ o3,
          int n4)
{
    const float* in; unsigned short* out;
    switch (blockIdx.y) {
        case 0: in = i0; out = o0; break;
        case 1: in = i1; out = o1; break;
        case 2: in = i2; out = o2; break;
        default: in = i3; out = o3; break;
    }
    int i = blockIdx.x * 256 + threadIdx.x;
    if (i < n4) {
        float4 v = ((const float4*)in)[i];
        ushort4 r;
        r.x = f2bf(v.x); r.y = f2bf(v.y); r.z = f2bf(v.z); r.w = f2bf(v.w);
        ((ushort4*)out)[i] = r;
    }
}

// ---------------------------------------------------------------------------
// 128x64-tile bf16-MFMA GEMM, DMA-STAGED (global_load_lds width 16).
// LDS 16B slot s of a tile row r=s>>3 holds chunk cc=(s&7)^(r&7); read side
// uses the matching XOR swizzle (proven r7-r12).
// ---------------------------------------------------------------------------
__global__ __launch_bounds__(256, 3)
void gemm128(const unsigned short* __restrict__ x0, const unsigned short* __restrict__ x1,
             const unsigned short* __restrict__ x2,
             const unsigned short* __restrict__ w0, const unsigned short* __restrict__ w1,
             const unsigned short* __restrict__ w2,
             const float* __restrict__ b0, const float* __restrict__ b1,
             const float* __restrict__ b2,
             void* __restrict__ o0v, void* __restrict__ o1v, void* __restrict__ o2v,
             float s0, float s1, float s2, int m0, int m1, int m2)
{
    const unsigned short* X; const unsigned short* W; const float* bias; void* outv;
    float scale; int mode;
    switch (blockIdx.z) {
        case 0:  X = x0; W = w0; bias = b0; outv = o0v; scale = s0; mode = m0; break;
        case 1:  X = x1; W = w1; bias = b1; outv = o1v; scale = s1; mode = m1; break;
        default: X = x2; W = w2; bias = b2; outv = o2v; scale = s2; mode = m2; break;
    }

    __shared__ unsigned short Xs[2][128 * 64];
    __shared__ unsigned short Ws[2][64 * 64];

    const int tid = threadIdx.x;
    const int w = tid >> 6, lane = tid & 63, ln = lane & 15, qd = lane >> 4;
    const int wm = (w >> 1) * 64, wn = (w & 1) * 32;
    const int row0 = blockIdx.x * 128, col0 = blockIdx.y * 64;

    f32x4 acc[4][2];
#pragma unroll
    for (int mt = 0; mt < 4; ++mt)
#pragma unroll
        for (int nt = 0; nt < 2; ++nt) acc[mt][nt] = f32x4{0.f, 0.f, 0.f, 0.f};

    // DMA stage: linear LDS dest (wave-uniform base + lane*16), source
    // inverse-swizzled so LDS bytes match the old XOR-swizzled layout.
    auto stage = [&](int buf, int k0) {
#pragma unroll
        for (int c = 0; c < 4; ++c) {              // X tile: 1024 slots
            const int s = c * 256 + w * 64 + lane;
            const int r = s >> 3, cc = (s & 7) ^ (r & 7);
            const unsigned short* gs = X + (size_t)(row0 + r) * 512 + k0 + cc * 8;
            __builtin_amdgcn_global_load_lds(
                (const __attribute__((address_space(1))) unsigned int*)gs,
                (__attribute__((address_space(3))) unsigned int*)
                    ((char*)&Xs[buf][0] + (c * 256 + w * 64) * 16),
                16, 0, 0);
        }
#pragma unroll
        for (int c = 0; c < 2; ++c) {              // W tile: 512 slots
            const int s = c * 256 + w * 64 + lane;
            const int r = s >> 3, cc = (s & 7) ^ (r & 7);
            const unsigned short* gs = W + (size_t)(col0 + r) * 512 + k0 + cc * 8;
            __builtin_amdgcn_global_load_lds(
                (const __attribute__((address_space(1))) unsigned int*)gs,
                (__attribute__((address_space(3))) unsigned int*)
                    ((char*)&Ws[buf][0] + (c * 256 + w * 64) * 16),
                16, 0, 0);
        }
    };

    stage(0, 0);
    for (int k0 = 0; k0 < 512; k0 += 64) {
        const int buf = (k0 >> 6) & 1;
        __syncthreads();                 // drains prev DMA (vmcnt) + buf reuse
        if (k0 + 64 < 512) stage(buf ^ 1, k0 + 64);
#pragma unroll
        for (int kc = 0; kc < 2; ++kc) {
            s16x8 af[4], bfr[2];
#pragma unroll
            for (int mt = 0; mt < 4; ++mt) {
                int r = wm + mt * 16 + ln;
                af[mt] = *(const s16x8*)&Xs[buf][r * 64 + (((kc * 4 + qd) ^ (ln & 7)) * 8)];
            }
#pragma unroll
            for (int nt = 0; nt < 2; ++nt) {
                int r = wn + nt * 16 + ln;
                bfr[nt] = *(const s16x8*)&Ws[buf][r * 64 + (((kc * 4 + qd) ^ (ln & 7)) * 8)];
            }
#pragma unroll
            for (int mt = 0; mt < 4; ++mt)
#pragma unroll
                for (int nt = 0; nt < 2; ++nt)
                    acc[mt][nt] = __builtin_amdgcn_mfma_f32_16x16x32_bf16(
                        af[mt], bfr[nt], acc[mt][nt], 0, 0, 0);
        }
    }

#pragma unroll
    for (int nt = 0; nt < 2; ++nt) {
        const int n = col0 + wn + nt * 16 + ln;
        const float bz = bias[n];
#pragma unroll
        for (int mt = 0; mt < 4; ++mt) {
            const int mbase = row0 + wm + mt * 16 + qd * 4;
            if (mode == 0) {
                float* o = (float*)outv;
#pragma unroll
                for (int r = 0; r < 4; ++r)
                    o[(size_t)(mbase + r) * 512 + n] = acc[mt][nt][r] + bz;
            } else if (mode == 1) {
                unsigned short* o = (unsigned short*)outv;
                const int h = n >> 6, dk = n & 63;
#pragma unroll
                for (int r = 0; r < 4; ++r) {
                    int m = mbase + r, b = m >> 11, s = m & 2047;
                    o[((size_t)(b * Hc + h) * Sc + s) * 64 + dk] =
                        f2bf((acc[mt][nt][r] + bz) * scale);
                }
            } else {
                unsigned short* o = (unsigned short*)outv;
                const int h = n >> 6, dk = n & 63;
                const int b = mbase >> 11, sb = mbase & 2047;
                const int ss = (sb & ~12) | ((sb & 4) << 1) | ((sb & 8) >> 1); // swap bits 2,3
                ushort4 pk;
                pk.x = f2bf((acc[mt][nt][0] + bz) * scale);
                pk.y = f2bf((acc[mt][nt][1] + bz) * scale);
                pk.z = f2bf((acc[mt][nt][2] + bz) * scale);
                pk.w = f2bf((acc[mt][nt][3] + bz) * scale);
                *(ushort4*)(o + ((size_t)(b * Hc + h) * 64 + dk) * Sc + ss) = pk;
            }
        }
    }
}

// ---------------------------------------------------------------------------
// Split-K bf16 32x32x16-MFMA flash attention, max-free softmax,
// single-q-stream, DMA-STAGED. r12 counters: VALU 49.6%, Mfma 18.1%,
// Occ 33% (= the 3 blocks/CU we asked for), WRITE 8.2MB (no spill),
// VGPR 64 arch + 48 acc = 112. This round: launch_bounds(256,4) ->
// 4 blocks/CU (16 waves/CU). Safe now that DMA staging cut arch demand
// to 64: budget 128 >= 112 -> no spill expected (r9/r10 spilled because
// arch demand was ~90-110 with reg-staging).
// Spill tripwire: WRITE_SIZE must stay ~8.2 MB.
// ---------------------------------------------------------------------------
__global__ __launch_bounds__(256, 4)
void attn_mfma(const unsigned short* __restrict__ qh, const unsigned short* __restrict__ kh,
               const unsigned short* __restrict__ vt, const unsigned* __restrict__ mbits,
               unsigned short* __restrict__ ctx)
{
    __shared__ uint4 smem4[2][1024];   // 2 x 16384 B = 32 KB

    const int bh = blockIdx.y, b = bh >> 3, h = bh & 7;
    const int q0 = blockIdx.x * 64;
    const int tid = threadIdx.x;
    const int w = tid >> 6;
    const int g = w >> 1;            // q-tile
    const int kh_ = w & 1;           // key half
    const int lane = tid & 63, ln = lane & 31, hf = lane >> 5;
    const int wv = tid >> 7;         // wave index within kh-group (0/1)
    const int qr = q0 + g * 32 + ln;

    // Q B-frags, resident (single tile)
    s16x8 qf[4];
    {
        const unsigned short* qp = qh + ((size_t)bh * Sc + qr) * 64 + hf * 8;
#pragma unroll
        for (int kc = 0; kc < 4; ++kc)
            qf[kc] = *(const s16x8*)(qp + kc * 16);
    }

    f32x16 o0, o1;
#pragma unroll
    for (int r = 0; r < 16; ++r) { o0[r] = 0.f; o1[r] = 0.f; }
    float lr = 0.f;

    const unsigned* mr = mbits + ((size_t)b * Sc + qr) * (Sc / 32);
    const unsigned short* kbase = kh + (size_t)bh * Sc * 64;
    const unsigned short* vbase = vt + (size_t)bh * 64 * Sc;

    const int kt0 = kh_ * 1024;

    // DMA stage: linear LDS dest (wave base + lane*16), inverse-swizzled
    // global source. Per kh-group: 8 KB = K 4KB (4 segs) + V 4KB (4 segs);
    // each of the group's 2 waves DMAs 2 K-segs + 2 V-segs of 1 KB.
    auto stage_tile = [&](int buf, int kt) {
        char* gb = (char*)smem4[buf] + kh_ * 8192;
#pragma unroll
        for (int c = 0; c < 2; ++c) {
            const int seg = wv * 2 + c;                  // wave-uniform
            const int s   = seg * 64 + lane;             // linear 16B slot
            const int r   = s >> 3, cc = (s & 7) ^ (r & 7);
            const unsigned short* gs = kbase + (size_t)(kt + r) * 64 + cc * 8;
            __builtin_amdgcn_global_load_lds(
                (const __attribute__((address_space(1))) unsigned int*)gs,
                (__attribute__((address_space(3))) unsigned int*)(gb + seg * 1024),
                16, 0, 0);
        }
        char* vb = gb + 4096;
#pragma unroll
        for (int c = 0; c < 2; ++c) {
            const int seg = wv * 2 + c;                  // = cc (chunk index)
            const int dv  = lane ^ (seg << 1);
            const unsigned short* gs = vbase + (size_t)dv * Sc + kt + seg * 8;
            __builtin_amdgcn_global_load_lds(
                (const __attribute__((address_space(1))) unsigned int*)gs,
                (__attribute__((address_space(3))) unsigned int*)(vb + seg * 1024),
                16, 0, 0);
        }
    };

    stage_tile(0, kt0);
    unsigned mwn = mr[kt0 >> 5];

    for (int i = 0; i < 32; ++i) {
        const int kt = kt0 + i * 32;
        const int buf = i & 1;
        __syncthreads();          // drains this wave's DMA (vmcnt) + orders buf reuse
        const unsigned mw = mwn;
        if (i < 31) {
            stage_tile(buf ^ 1, kt + 32);
            mwn = mr[(kt + 32) >> 5];
        }

        const unsigned short* Ks = (const unsigned short*)smem4[buf] + kh_ * 4096;
        const unsigned short* Vs = Ks + 2048;

        // ---- S^T[key][q] = K · Q^T
        f32x16 sv;
#pragma unroll
        for (int r = 0; r < 16; ++r) sv[r] = 0.f;
        __builtin_amdgcn_s_setprio(1);
#pragma unroll
        for (int kc = 0; kc < 4; ++kc) {
            s16x8 kf = *(const s16x8*)&Ks[ln * 64 + ((((kc << 1) | hf) ^ (ln & 7)) * 8)];
            sv = __builtin_amdgcn_mfma_f32_32x32x16_bf16(kf, qf[kc], sv, 0, 0, 0);
        }
        __builtin_amdgcn_s_setprio(0);

        // ---- mask + exp2 (no max: scores bounded), pack to bf16 pairs
        float ps = 0.f;
        unsigned pu[8];
#pragma unroll
        for (int r = 0; r < 16; r += 2) {
            int key0 = (r & 3) + 8 * (r >> 2) + 4 * hf;
            int key1 = ((r + 1) & 3) + 8 * ((r + 1) >> 2) + 4 * hf;
            float a0 = ((mw >> key0) & 1u) ? sv[r]     : -1e9f;
            float a1 = ((mw >> key1) & 1u) ? sv[r + 1] : -1e9f;
            float p0 = fexp2(a0), p1 = fexp2(a1);
            ps += p0 + p1;
            pu[r >> 1] = (unsigned)f2bf(p0) | ((unsigned)f2bf(p1) << 16);
        }
        lr += ps;

        // ---- ctx^T[dv][q] += V · P^T
        __builtin_amdgcn_s_setprio(1);
#pragma unroll
        for (int kc = 0; kc < 2; ++kc) {
            uint4 ua; ua.x = pu[4*kc]; ua.y = pu[4*kc+1]; ua.z = pu[4*kc+2]; ua.w = pu[4*kc+3];
            s16x8 pf = __builtin_bit_cast(s16x8, ua);
            const int cc = (kc << 1) | hf;
            s16x8 v0  = *(const s16x8*)&Vs[(cc * 64 + (ln ^ (cc << 1))) * 8];
            s16x8 v1  = *(const s16x8*)&Vs[(cc * 64 + ((32 + ln) ^ (cc << 1))) * 8];
            o0 = __builtin_amdgcn_mfma_f32_32x32x16_bf16(v0, pf, o0, 0, 0, 0);
            o1 = __builtin_amdgcn_mfma_f32_32x32x16_bf16(v1, pf, o1, 0, 0, 0);
        }
        __builtin_amdgcn_s_setprio(0);
    }

    // l per-hf partial -> full
    lr += __shfl_xor(lr, 32);

    // ---- cross-half combine (linear). kh=1 -> LDS, kh=0 adds + writes.
    // Region [128][48] f32 = 24576 B; float4 slot q stored at (q ^ (row&7)):
    // 8 lanes cover all 32 banks -> conflict-free.
    __syncthreads();
    float* cs = (float*)smem4[0];
    const int row = g * 64 + lane;
    float* my = cs + (size_t)row * 48;
    const int sw = lane & 7;
    if (kh_ == 1) {
#pragma unroll
        for (int r = 0; r < 4; ++r) {
            *(float4*)(my + ((r ^ sw) * 4))       = make_float4(o0[4*r], o0[4*r+1], o0[4*r+2], o0[4*r+3]);
            *(float4*)(my + (((r + 4) ^ sw) * 4)) = make_float4(o1[4*r], o1[4*r+1], o1[4*r+2], o1[4*r+3]);
        }
        my[32] = lr;
    }
    __syncthreads();
    if (kh_ == 0) {
        lr += my[32];
        const float inv = 1.f / lr;
#pragma unroll
        for (int r = 0; r < 4; ++r) {
            float4 a0 = *(const float4*)(my + ((r ^ sw) * 4));
            float4 a1 = *(const float4*)(my + (((r + 4) ^ sw) * 4));
            o0[4*r]   = (o0[4*r]   + a0.x) * inv; o0[4*r+1] = (o0[4*r+1] + a0.y) * inv;
            o0[4*r+2] = (o0[4*r+2] + a0.z) * inv; o0[4*r+3] = (o0[4*r+3] + a0.w) * inv;
            o1[4*r]   = (o1[4*r]   + a1.x) * inv; o1[4*r+1] = (o1[4*r+1] + a1.y) * inv;
            o1[4*r+2] = (o1[4*r+2] + a1.z) * inv; o1[4*r+3] = (o1[4*r+3] + a1.w) * inv;
        }
        // ctx bf16 [B,S,D]; dv = 8*gg + 4*hf + t (+32 for the o1 half)
        unsigned short* op = ctx + ((size_t)(b * Sc + qr)) * 512 + h * 64;
#pragma unroll
        for (int gg = 0; gg < 4; ++gg) {
            ushort4 a, c;
            a.x = f2bf(o0[gg*4+0]); a.y = f2bf(o0[gg*4+1]);
            a.z = f2bf(o0[gg*4+2]); a.w = f2bf(o0[gg*4+3]);
            c.x = f2bf(o1[gg*4+0]); c.y = f2bf(o1[gg*4+1]);
            c.z = f2bf(o1[gg*4+2]); c.w = f2bf(o1[gg*4+3]);
            *(ushort4*)(op + 8 * gg + 4 * hf)      = a;
            *(ushort4*)(op + 32 + 8 * gg + 4 * hf) = c;
        }
    }
}

// ---------------------------------------------------------------------------
extern "C" void kernel_launch(void* const* d_in, const int* in_sizes, int n_in,
                              void* d_out, int out_size, void* d_ws, size_t ws_size,
                              hipStream_t stream)
{
    (void)in_sizes; (void)n_in; (void)out_size; (void)ws_size;

    const float* q    = (const float*)d_in[0];
    const float* k    = (const float*)d_in[1];
    const float* v    = (const float*)d_in[2];
    const int*   mask = (const int*)  d_in[3];
    const float* Wq   = (const float*)d_in[4];
    const float* bq   = (const float*)d_in[5];
    const float* Wk   = (const float*)d_in[6];
    const float* bk   = (const float*)d_in[7];
    const float* Wv   = (const float*)d_in[8];
    const float* bv   = (const float*)d_in[9];
    const float* Wo   = (const float*)d_in[10];
    const float* bo   = (const float*)d_in[11];
    float* out = (float*)d_out;

    // workspace carve; TEN = 4,194,304 elems
    constexpr size_t TEN = (size_t)Bc * Hc * Sc * DKc;
    char* p = (char*)d_ws;
    unsigned short* wqb   = (unsigned short*)p;  p += (size_t)Dc * Dc * 2;  // 0.5 MB
    unsigned short* wkb   = (unsigned short*)p;  p += (size_t)Dc * Dc * 2;
    unsigned short* wvb   = (unsigned short*)p;  p += (size_t)Dc * Dc * 2;
    unsigned short* wob   = (unsigned short*)p;  p += (size_t)Dc * Dc * 2;
    unsigned short* qh_bf = (unsigned short*)p;  p += TEN * 2;              // 8 MB
    unsigned short* kh_bf = (unsigned short*)p;  p += TEN * 2;
    unsigned short* vt_bf = (unsigned short*)p;  p += TEN * 2;
    unsigned short* ctx   = (unsigned short*)p;  p += TEN * 2;
    unsigned long long* mb64 = (unsigned long long*)p;                      // 2 MB

    // bf16 copies of q,k,v — ZERO workspace cost via aliasing:
    //   qb,kb live in d_out (16 MB, dead until the final GEMM writes it);
    //   vb lives in ctx (written only later, by attn, after QKV reads vb).
    unsigned short* qb = (unsigned short*)d_out;
    unsigned short* kb = qb + TEN;
    unsigned short* vb = ctx;

    const int nwords = Bc * Sc * (Sc / 64);   // 262144

    dim3 bb(256);

    pack_mask<<<dim3(16384), bb, 0, stream>>>(mask, mb64, nwords);
    // weights fp32->bf16 (4 tensors, 64K float4s each)
    cvt4<<<dim3(Dc * Dc / 4 / 256, 4), bb, 0, stream>>>(Wq, Wk, Wv, Wo, wqb, wkb, wvb, wob,
                                                        Dc * Dc / 4);
    // activations fp32->bf16 (3 tensors, 1M float4s each)
    cvt4<<<dim3((int)(TEN / 4 / 256), 3), bb, 0, stream>>>(q, k, v, v, qb, kb, vb, vb,
                                                           (int)(TEN / 4));
    // merged Q/K/V projections: one dispatch, 1536 blocks, 3 blocks/CU
    gemm128<<<dim3(Mc / 128, Dc / 64, 3), bb, 0, stream>>>(
        qb, kb, vb, wqb, wkb, wvb, bq, bk, bv, qh_bf, kh_bf, vt_bf,
        SCALE_Q, 1.0f, 1.0f, 1, 1, 2);
    attn_mfma<<<dim3(Sc / 64, Bc * Hc), bb, 0, stream>>>(qh_bf, kh_bf, vt_bf,
                                                         (const unsigned*)mb64, ctx);
    gemm128<<<dim3(Mc / 128, Dc / 64, 1), bb, 0, stream>>>(
        ctx, ctx, ctx, wob, wob, wob, bo, bo, bo, out, out, out,
        1.0f, 1.0f, 1.0f, 0, 0, 0);
}

// Round 6
// 265.697 us; speedup vs baseline: 1.0139x; 1.0139x over previous
//
#include <hip/hip_runtime.h>
#include <math.h>

// Problem constants
constexpr int Bc  = 4;
constexpr int Sc  = 2048;
constexpr int Dc  = 512;
constexpr int Hc  = 8;
constexpr int DKc = 64;
constexpr int Mc  = Bc * Sc;   // 8192 rows

constexpr float SCALE_Q = 0.180336880111120426f;   // (1/8) * log2(e): /H quirk + exp2 base

typedef __attribute__((ext_vector_type(8)))  short s16x8;   // 8 bf16 MFMA frag
typedef __attribute__((ext_vector_type(4)))  float f32x4;   // 16x16 accumulator
typedef __attribute__((ext_vector_type(16))) float f32x16;  // 32x32 accumulator

__device__ __forceinline__ unsigned short f2bf(float f) {
    __bf16 h = (__bf16)f;                 // RNE convert
    return __builtin_bit_cast(unsigned short, h);
}

__device__ __forceinline__ float fexp2(float x) {
#if __has_builtin(__builtin_amdgcn_exp2f)
    return __builtin_amdgcn_exp2f(x);
#else
    return __expf(x * 0.6931471805599453f);
#endif
}

// ---------------------------------------------------------------------------
// mask [B,1,S,S] int32 -> keep-bit words: bit j of word w == (mask[w*64+j]!=0)
// ---------------------------------------------------------------------------
__global__ __launch_bounds__(256)
void pack_mask(const int* __restrict__ mask, unsigned long long* __restrict__ out,
               int nwords)
{
    int gw   = (blockIdx.x * blockDim.x + threadIdx.x) >> 6;
    int lane = threadIdx.x & 63;
    int nw   = (gridDim.x * blockDim.x) >> 6;
    for (int w0 = gw * 4; w0 < nwords; w0 += nw * 4) {
        int vals[4];
#pragma unroll
        for (int c = 0; c < 4; ++c)
            vals[c] = mask[(size_t)(w0 + c) * 64 + lane];
#pragma unroll
        for (int c = 0; c < 4; ++c) {
            unsigned long long bits = __ballot(vals[c] != 0);
            if (lane == 0) out[w0 + c] = bits;
        }
    }
}

// ---------------------------------------------------------------------------
// fp32 -> bf16 elementwise, up to 4 tensors (blockIdx.y selects), n4 float4s
// ---------------------------------------------------------------------------
__global__ __launch_bounds__(256)
void cvt4(const float* __restrict__ i0, const float* __restrict__ i1,
          const float* __restrict__ i2, const float* __restrict__ i3,
          unsigned short* __restrict__ o0, unsigned short* __restrict__ o1,
          unsigned short* __restrict__ o2, unsigned short* __restrict__ o3,
          int n4)
{
    const float* in; unsigned short* out;
    switch (blockIdx.y) {
        case 0: in = i0; out = o0; break;
        case 1: in = i1; out = o1; break;
        case 2: in = i2; out = o2; break;
        default: in = i3; out = o3; break;
    }
    int i = blockIdx.x * 256 + threadIdx.x;
    if (i < n4) {
        float4 v = ((const float4*)in)[i];
        ushort4 r;
        r.x = f2bf(v.x); r.y = f2bf(v.y); r.z = f2bf(v.z); r.w = f2bf(v.w);
        ((ushort4*)out)[i] = r;
    }
}

// ---------------------------------------------------------------------------
// 128x64-tile bf16-MFMA GEMM, DMA-STAGED (global_load_lds width 16).
// LDS 16B slot s of a tile row r=s>>3 holds chunk cc=(s&7)^(r&7); read side
// uses the matching XOR swizzle (proven r7-r13).
//
// r13 fix: modes 1/2 wrote scattered 2-8B pieces -> 73MB WRITE for 24MB of
// output (mode 2's 8B at 4KB lane stride = 8x amplification + partial-line
// RMW). New epilogue: stage the block's 128x64 bf16 tile in LDS (Xs is dead
// after the K-loop), then write cooperative full 64B lines. Output bytes
// are identical to the old layout (incl. the mode-2 swap-bits-2,3 perm).
// ---------------------------------------------------------------------------
__global__ __launch_bounds__(256, 3)
void gemm128(const unsigned short* __restrict__ x0, const unsigned short* __restrict__ x1,
             const unsigned short* __restrict__ x2,
             const unsigned short* __restrict__ w0, const unsigned short* __restrict__ w1,
             const unsigned short* __restrict__ w2,
             const float* __restrict__ b0, const float* __restrict__ b1,
             const float* __restrict__ b2,
             void* __restrict__ o0v, void* __restrict__ o1v, void* __restrict__ o2v,
             float s0, float s1, float s2, int m0, int m1, int m2)
{
    const unsigned short* X; const unsigned short* W; const float* bias; void* outv;
    float scale; int mode;
    switch (blockIdx.z) {
        case 0:  X = x0; W = w0; bias = b0; outv = o0v; scale = s0; mode = m0; break;
        case 1:  X = x1; W = w1; bias = b1; outv = o1v; scale = s1; mode = m1; break;
        default: X = x2; W = w2; bias = b2; outv = o2v; scale = s2; mode = m2; break;
    }

    __shared__ unsigned short Xs[2][128 * 64];
    __shared__ unsigned short Ws[2][64 * 64];

    const int tid = threadIdx.x;
    const int w = tid >> 6, lane = tid & 63, ln = lane & 15, qd = lane >> 4;
    const int wm = (w >> 1) * 64, wn = (w & 1) * 32;
    const int row0 = blockIdx.x * 128, col0 = blockIdx.y * 64;

    f32x4 acc[4][2];
#pragma unroll
    for (int mt = 0; mt < 4; ++mt)
#pragma unroll
        for (int nt = 0; nt < 2; ++nt) acc[mt][nt] = f32x4{0.f, 0.f, 0.f, 0.f};

    // DMA stage: linear LDS dest (wave-uniform base + lane*16), source
    // inverse-swizzled so LDS bytes match the old XOR-swizzled layout.
    auto stage = [&](int buf, int k0) {
#pragma unroll
        for (int c = 0; c < 4; ++c) {              // X tile: 1024 slots
            const int s = c * 256 + w * 64 + lane;
            const int r = s >> 3, cc = (s & 7) ^ (r & 7);
            const unsigned short* gs = X + (size_t)(row0 + r) * 512 + k0 + cc * 8;
            __builtin_amdgcn_global_load_lds(
                (const __attribute__((address_space(1))) unsigned int*)gs,
                (__attribute__((address_space(3))) unsigned int*)
                    ((char*)&Xs[buf][0] + (c * 256 + w * 64) * 16),
                16, 0, 0);
        }
#pragma unroll
        for (int c = 0; c < 2; ++c) {              // W tile: 512 slots
            const int s = c * 256 + w * 64 + lane;
            const int r = s >> 3, cc = (s & 7) ^ (r & 7);
            const unsigned short* gs = W + (size_t)(col0 + r) * 512 + k0 + cc * 8;
            __builtin_amdgcn_global_load_lds(
                (const __attribute__((address_space(1))) unsigned int*)gs,
                (__attribute__((address_space(3))) unsigned int*)
                    ((char*)&Ws[buf][0] + (c * 256 + w * 64) * 16),
                16, 0, 0);
        }
    };

    stage(0, 0);
    for (int k0 = 0; k0 < 512; k0 += 64) {
        const int buf = (k0 >> 6) & 1;
        __syncthreads();                 // drains prev DMA (vmcnt) + buf reuse
        if (k0 + 64 < 512) stage(buf ^ 1, k0 + 64);
#pragma unroll
        for (int kc = 0; kc < 2; ++kc) {
            s16x8 af[4], bfr[2];
#pragma unroll
            for (int mt = 0; mt < 4; ++mt) {
                int r = wm + mt * 16 + ln;
                af[mt] = *(const s16x8*)&Xs[buf][r * 64 + (((kc * 4 + qd) ^ (ln & 7)) * 8)];
            }
#pragma unroll
            for (int nt = 0; nt < 2; ++nt) {
                int r = wn + nt * 16 + ln;
                bfr[nt] = *(const s16x8*)&Ws[buf][r * 64 + (((kc * 4 + qd) ^ (ln & 7)) * 8)];
            }
#pragma unroll
            for (int mt = 0; mt < 4; ++mt)
#pragma unroll
                for (int nt = 0; nt < 2; ++nt)
                    acc[mt][nt] = __builtin_amdgcn_mfma_f32_16x16x32_bf16(
                        af[mt], bfr[nt], acc[mt][nt], 0, 0, 0);
        }
    }

    if (mode == 0) {
        // fp32 [M,512] rows: 16 lanes x 4B = 64B contiguous -> already fine
#pragma unroll
        for (int nt = 0; nt < 2; ++nt) {
            const int n = col0 + wn + nt * 16 + ln;
            const float bz = bias[n];
#pragma unroll
            for (int mt = 0; mt < 4; ++mt) {
                const int mbase = row0 + wm + mt * 16 + qd * 4;
                float* o = (float*)outv;
#pragma unroll
                for (int r = 0; r < 4; ++r)
                    o[(size_t)(mbase + r) * 512 + n] = acc[mt][nt][r] + bz;
            }
        }
    } else if (mode == 1) {
        // [B,H,S,dk] bf16 via LDS tile T[128][72] (s-major), then 64B lines
        __syncthreads();                       // all Xs/Ws reads done
        unsigned short* T = &Xs[0][0];
#pragma unroll
        for (int nt = 0; nt < 2; ++nt) {
            const int n = col0 + wn + nt * 16 + ln;
            const float bz = bias[n];
            const int dk = n & 63;
#pragma unroll
            for (int mt = 0; mt < 4; ++mt) {
                const int ml = wm + mt * 16 + qd * 4;
#pragma unroll
                for (int r = 0; r < 4; ++r)
                    T[(ml + r) * 72 + dk] = f2bf((acc[mt][nt][r] + bz) * scale);
            }
        }
        __syncthreads();
        const int sl = tid >> 1, halfo = (tid & 1) * 32;
        const int h = col0 >> 6, bb = row0 >> 11, sm = row0 & 2047;
        const unsigned short* Tr = &T[sl * 72 + halfo];
        uint4 d0 = *(const uint4*)(Tr);
        uint4 d1 = *(const uint4*)(Tr + 8);
        uint4 d2 = *(const uint4*)(Tr + 16);
        uint4 d3 = *(const uint4*)(Tr + 24);
        unsigned short* o = (unsigned short*)outv +
                            ((size_t)(bb * Hc + h) * Sc + sm + sl) * 64 + halfo;
        *(uint4*)(o)      = d0;
        *(uint4*)(o + 8)  = d1;
        *(uint4*)(o + 16) = d2;
        *(uint4*)(o + 24) = d3;
    } else {
        // [B,H,dk,S] bf16 (swap-bits-2,3 s-perm) via T2[64][136] (dk-major)
        __syncthreads();
        unsigned short* T2 = &Xs[0][0];
#pragma unroll
        for (int nt = 0; nt < 2; ++nt) {
            const int n = col0 + wn + nt * 16 + ln;
            const float bz = bias[n];
            const int dk = n & 63;
#pragma unroll
            for (int mt = 0; mt < 4; ++mt) {
                const int ml = wm + mt * 16 + qd * 4;
                const int sw = (ml & ~12) | ((ml & 4) << 1) | ((ml & 8) >> 1);
#pragma unroll
                for (int r = 0; r < 4; ++r)
                    T2[dk * 136 + sw + r] = f2bf((acc[mt][nt][r] + bz) * scale);
            }
        }
        __syncthreads();
        const int dv = tid >> 2, qo = (tid & 3) * 32;
        const int h = col0 >> 6, bb = row0 >> 11, sm = row0 & 2047;
        const unsigned short* Tr = &T2[dv * 136 + qo];
        uint4 d0 = *(const uint4*)(Tr);
        uint4 d1 = *(const uint4*)(Tr + 8);
        uint4 d2 = *(const uint4*)(Tr + 16);
        uint4 d3 = *(const uint4*)(Tr + 24);
        unsigned short* o = (unsigned short*)outv +
                            ((size_t)(bb * Hc + h) * 64 + dv) * Sc + sm + qo;
        *(uint4*)(o)      = d0;
        *(uint4*)(o + 8)  = d1;
        *(uint4*)(o + 16) = d2;
        *(uint4*)(o + 24) = d3;
    }
}

// ---------------------------------------------------------------------------
// Split-K bf16 32x32x16-MFMA flash attention, max-free softmax,
// single-q-stream, DMA-STAGED. r14 adds T1 XCD-aware swizzle: physical
// dispatch round-robins XCDs, so the 32 q-blocks sharing one bh's K/V
// (512 KB) were spread over all 8 XCD L2s (FETCH 70MB vs 26MB ideal).
// Bijective remap (1024 wgs % 8 == 0) clusters 4 bh per XCD -> 2MB in L2.
// Inner loop untouched (r12-proven; WRITE 8.2MB = no spill).
// ---------------------------------------------------------------------------
__global__ __launch_bounds__(256, 4)
void attn_mfma(const unsigned short* __restrict__ qh, const unsigned short* __restrict__ kh,
               const unsigned short* __restrict__ vt, const unsigned* __restrict__ mbits,
               unsigned short* __restrict__ ctx)
{
    __shared__ uint4 smem4[2][1024];   // 2 x 16384 B = 32 KB

    // T1 XCD swizzle: physical wg p -> XCD p%8; give each XCD a contiguous
    // logical chunk of 128 wgs (= 4 complete bh groups).
    const int pwg = blockIdx.y * gridDim.x + blockIdx.x;
    const int lg  = (pwg & 7) * 128 + (pwg >> 3);
    const int bh = lg >> 5, b = bh >> 3, h = bh & 7;
    const int q0 = (lg & 31) * 64;

    const int tid = threadIdx.x;
    const int w = tid >> 6;
    const int g = w >> 1;            // q-tile
    const int kh_ = w & 1;           // key half
    const int lane = tid & 63, ln = lane & 31, hf = lane >> 5;
    const int wv = tid >> 7;         // wave index within kh-group (0/1)
    const int qr = q0 + g * 32 + ln;

    // Q B-frags, resident (single tile)
    s16x8 qf[4];
    {
        const unsigned short* qp = qh + ((size_t)bh * Sc + qr) * 64 + hf * 8;
#pragma unroll
        for (int kc = 0; kc < 4; ++kc)
            qf[kc] = *(const s16x8*)(qp + kc * 16);
    }

    f32x16 o0, o1;
#pragma unroll
    for (int r = 0; r < 16; ++r) { o0[r] = 0.f; o1[r] = 0.f; }
    float lr = 0.f;

    const unsigned* mr = mbits + ((size_t)b * Sc + qr) * (Sc / 32);
    const unsigned short* kbase = kh + (size_t)bh * Sc * 64;
    const unsigned short* vbase = vt + (size_t)bh * 64 * Sc;

    const int kt0 = kh_ * 1024;

    // DMA stage: linear LDS dest (wave base + lane*16), inverse-swizzled
    // global source. Per kh-group: 8 KB = K 4KB (4 segs) + V 4KB (4 segs);
    // each of the group's 2 waves DMAs 2 K-segs + 2 V-segs of 1 KB.
    auto stage_tile = [&](int buf, int kt) {
        char* gb = (char*)smem4[buf] + kh_ * 8192;
#pragma unroll
        for (int c = 0; c < 2; ++c) {
            const int seg = wv * 2 + c;                  // wave-uniform
            const int s   = seg * 64 + lane;             // linear 16B slot
            const int r   = s >> 3, cc = (s & 7) ^ (r & 7);
            const unsigned short* gs = kbase + (size_t)(kt + r) * 64 + cc * 8;
            __builtin_amdgcn_global_load_lds(
                (const __attribute__((address_space(1))) unsigned int*)gs,
                (__attribute__((address_space(3))) unsigned int*)(gb + seg * 1024),
                16, 0, 0);
        }
        char* vb = gb + 4096;
#pragma unroll
        for (int c = 0; c < 2; ++c) {
            const int seg = wv * 2 + c;                  // = cc (chunk index)
            const int dv  = lane ^ (seg << 1);
            const unsigned short* gs = vbase + (size_t)dv * Sc + kt + seg * 8;
            __builtin_amdgcn_global_load_lds(
                (const __attribute__((address_space(1))) unsigned int*)gs,
                (__attribute__((address_space(3))) unsigned int*)(vb + seg * 1024),
                16, 0, 0);
        }
    };

    stage_tile(0, kt0);
    unsigned mwn = mr[kt0 >> 5];

    for (int i = 0; i < 32; ++i) {
        const int kt = kt0 + i * 32;
        const int buf = i & 1;
        __syncthreads();          // drains this wave's DMA (vmcnt) + orders buf reuse
        const unsigned mw = mwn;
        if (i < 31) {
            stage_tile(buf ^ 1, kt + 32);
            mwn = mr[(kt + 32) >> 5];
        }

        const unsigned short* Ks = (const unsigned short*)smem4[buf] + kh_ * 4096;
        const unsigned short* Vs = Ks + 2048;

        // ---- S^T[key][q] = K · Q^T
        f32x16 sv;
#pragma unroll
        for (int r = 0; r < 16; ++r) sv[r] = 0.f;
        __builtin_amdgcn_s_setprio(1);
#pragma unroll
        for (int kc = 0; kc < 4; ++kc) {
            s16x8 kf = *(const s16x8*)&Ks[ln * 64 + ((((kc << 1) | hf) ^ (ln & 7)) * 8)];
            sv = __builtin_amdgcn_mfma_f32_32x32x16_bf16(kf, qf[kc], sv, 0, 0, 0);
        }
        __builtin_amdgcn_s_setprio(0);

        // ---- mask + exp2 (no max: scores bounded), pack to bf16 pairs
        float ps = 0.f;
        unsigned pu[8];
#pragma unroll
        for (int r = 0; r < 16; r += 2) {
            int key0 = (r & 3) + 8 * (r >> 2) + 4 * hf;
            int key1 = ((r + 1) & 3) + 8 * ((r + 1) >> 2) + 4 * hf;
            float a0 = ((mw >> key0) & 1u) ? sv[r]     : -1e9f;
            float a1 = ((mw >> key1) & 1u) ? sv[r + 1] : -1e9f;
            float p0 = fexp2(a0), p1 = fexp2(a1);
            ps += p0 + p1;
            pu[r >> 1] = (unsigned)f2bf(p0) | ((unsigned)f2bf(p1) << 16);
        }
        lr += ps;

        // ---- ctx^T[dv][q] += V · P^T
        __builtin_amdgcn_s_setprio(1);
#pragma unroll
        for (int kc = 0; kc < 2; ++kc) {
            uint4 ua; ua.x = pu[4*kc]; ua.y = pu[4*kc+1]; ua.z = pu[4*kc+2]; ua.w = pu[4*kc+3];
            s16x8 pf = __builtin_bit_cast(s16x8, ua);
            const int cc = (kc << 1) | hf;
            s16x8 v0  = *(const s16x8*)&Vs[(cc * 64 + (ln ^ (cc << 1))) * 8];
            s16x8 v1  = *(const s16x8*)&Vs[(cc * 64 + ((32 + ln) ^ (cc << 1))) * 8];
            o0 = __builtin_amdgcn_mfma_f32_32x32x16_bf16(v0, pf, o0, 0, 0, 0);
            o1 = __builtin_amdgcn_mfma_f32_32x32x16_bf16(v1, pf, o1, 0, 0, 0);
        }
        __builtin_amdgcn_s_setprio(0);
    }

    // l per-hf partial -> full
    lr += __shfl_xor(lr, 32);

    // ---- cross-half combine (linear). kh=1 -> LDS, kh=0 adds + writes.
    // Region [128][48] f32 = 24576 B; float4 slot q stored at (q ^ (row&7)):
    // 8 lanes cover all 32 banks -> conflict-free.
    __syncthreads();
    float* cs = (float*)smem4[0];
    const int row = g * 64 + lane;
    float* my = cs + (size_t)row * 48;
    const int sw = lane & 7;
    if (kh_ == 1) {
#pragma unroll
        for (int r = 0; r < 4; ++r) {
            *(float4*)(my + ((r ^ sw) * 4))       = make_float4(o0[4*r], o0[4*r+1], o0[4*r+2], o0[4*r+3]);
            *(float4*)(my + (((r + 4) ^ sw) * 4)) = make_float4(o1[4*r], o1[4*r+1], o1[4*r+2], o1[4*r+3]);
        }
        my[32] = lr;
    }
    __syncthreads();
    if (kh_ == 0) {
        lr += my[32];
        const float inv = 1.f / lr;
#pragma unroll
        for (int r = 0; r < 4; ++r) {
            float4 a0 = *(const float4*)(my + ((r ^ sw) * 4));
            float4 a1 = *(const float4*)(my + (((r + 4) ^ sw) * 4));
            o0[4*r]   = (o0[4*r]   + a0.x) * inv; o0[4*r+1] = (o0[4*r+1] + a0.y) * inv;
            o0[4*r+2] = (o0[4*r+2] + a0.z) * inv; o0[4*r+3] = (o0[4*r+3] + a0.w) * inv;
            o1[4*r]   = (o1[4*r]   + a1.x) * inv; o1[4*r+1] = (o1[4*r+1] + a1.y) * inv;
            o1[4*r+2] = (o1[4*r+2] + a1.z) * inv; o1[4*r+3] = (o1[4*r+3] + a1.w) * inv;
        }
        // ctx bf16 [B,S,D]; dv = 8*gg + 4*hf + t (+32 for the o1 half)
        unsigned short* op = ctx + ((size_t)(b * Sc + qr)) * 512 + h * 64;
#pragma unroll
        for (int gg = 0; gg < 4; ++gg) {
            ushort4 a, c;
            a.x = f2bf(o0[gg*4+0]); a.y = f2bf(o0[gg*4+1]);
            a.z = f2bf(o0[gg*4+2]); a.w = f2bf(o0[gg*4+3]);
            c.x = f2bf(o1[gg*4+0]); c.y = f2bf(o1[gg*4+1]);
            c.z = f2bf(o1[gg*4+2]); c.w = f2bf(o1[gg*4+3]);
            *(ushort4*)(op + 8 * gg + 4 * hf)      = a;
            *(ushort4*)(op + 32 + 8 * gg + 4 * hf) = c;
        }
    }
}

// ---------------------------------------------------------------------------
extern "C" void kernel_launch(void* const* d_in, const int* in_sizes, int n_in,
                              void* d_out, int out_size, void* d_ws, size_t ws_size,
                              hipStream_t stream)
{
    (void)in_sizes; (void)n_in; (void)out_size; (void)ws_size;

    const float* q    = (const float*)d_in[0];
    const float* k    = (const float*)d_in[1];
    const float* v    = (const float*)d_in[2];
    const int*   mask = (const int*)  d_in[3];
    const float* Wq   = (const float*)d_in[4];
    const float* bq   = (const float*)d_in[5];
    const float* Wk   = (const float*)d_in[6];
    const float* bk   = (const float*)d_in[7];
    const float* Wv   = (const float*)d_in[8];
    const float* bv   = (const float*)d_in[9];
    const float* Wo   = (const float*)d_in[10];
    const float* bo   = (const float*)d_in[11];
    float* out = (float*)d_out;

    // workspace carve; TEN = 4,194,304 elems
    constexpr size_t TEN = (size_t)Bc * Hc * Sc * DKc;
    char* p = (char*)d_ws;
    unsigned short* wqb   = (unsigned short*)p;  p += (size_t)Dc * Dc * 2;  // 0.5 MB
    unsigned short* wkb   = (unsigned short*)p;  p += (size_t)Dc * Dc * 2;
    unsigned short* wvb   = (unsigned short*)p;  p += (size_t)Dc * Dc * 2;
    unsigned short* wob   = (unsigned short*)p;  p += (size_t)Dc * Dc * 2;
    unsigned short* qh_bf = (unsigned short*)p;  p += TEN * 2;              // 8 MB
    unsigned short* kh_bf = (unsigned short*)p;  p += TEN * 2;
    unsigned short* vt_bf = (unsigned short*)p;  p += TEN * 2;
    unsigned short* ctx   = (unsigned short*)p;  p += TEN * 2;
    unsigned long long* mb64 = (unsigned long long*)p;                      // 2 MB

    // bf16 copies of q,k,v — ZERO workspace cost via aliasing:
    //   qb,kb live in d_out (16 MB, dead until the final GEMM writes it);
    //   vb lives in ctx (written only later, by attn, after QKV reads vb).
    unsigned short* qb = (unsigned short*)d_out;
    unsigned short* kb = qb + TEN;
    unsigned short* vb = ctx;

    const int nwords = Bc * Sc * (Sc / 64);   // 262144

    dim3 bb(256);

    pack_mask<<<dim3(16384), bb, 0, stream>>>(mask, mb64, nwords);
    // weights fp32->bf16 (4 tensors, 64K float4s each)
    cvt4<<<dim3(Dc * Dc / 4 / 256, 4), bb, 0, stream>>>(Wq, Wk, Wv, Wo, wqb, wkb, wvb, wob,
                                                        Dc * Dc / 4);
    // activations fp32->bf16 (3 tensors, 1M float4s each)
    cvt4<<<dim3((int)(TEN / 4 / 256), 3), bb, 0, stream>>>(q, k, v, v, qb, kb, vb, vb,
                                                           (int)(TEN / 4));
    // merged Q/K/V projections: one dispatch, 1536 blocks, 3 blocks/CU
    gemm128<<<dim3(Mc / 128, Dc / 64, 3), bb, 0, stream>>>(
        qb, kb, vb, wqb, wkb, wvb, bq, bk, bv, qh_bf, kh_bf, vt_bf,
        SCALE_Q, 1.0f, 1.0f, 1, 1, 2);
    attn_mfma<<<dim3(Sc / 64, Bc * Hc), bb, 0, stream>>>(qh_bf, kh_bf, vt_bf,
                                                         (const unsigned*)mb64, ctx);
    gemm128<<<dim3(Mc / 128, Dc / 64, 1), bb, 0, stream>>>(
        ctx, ctx, ctx, wob, wob, wob, bo, bo, bo, out, out, out,
        1.0f, 1.0f, 1.0f, 0, 0, 0);
}